// Round 12
// baseline (961.368 us; speedup 1.0000x reference)
//
#include <hip/hip_runtime.h>
#include <math.h>

#define TOPK 8
#define NCORPUS 200000
#define BROWS 1024
#define CHUNK 512
#define NCHUNK 391           /* ceil(200000/512) */
#define NT 32                /* 4 subs * 8 K-steps (BK=64) */
#define NPART 4              /* per-chunk candidate depth */
#define NEGINF (-3.0e38f)

typedef __attribute__((ext_vector_type(8))) short bf16x8;
typedef __attribute__((ext_vector_type(4))) float f32x4;

__device__ __forceinline__ float wave_sum_f32(float v) {
#pragma unroll
  for (int m = 32; m >= 1; m >>= 1) v += __shfl_xor(v, m, 64);
  return v;
}
__device__ __forceinline__ double wave_sum_f64(double v) {
#pragma unroll
  for (int m = 32; m >= 1; m >>= 1) v += __shfl_xor(v, m, 64);
  return v;
}
__device__ __forceinline__ unsigned short f2bf(float f) {
  unsigned int u = __float_as_uint(f);
  unsigned int r = (u + 0x7fffu + ((u >> 16) & 1u)) >> 16;
  return (unsigned short)r;
}
__device__ __forceinline__ void gload16(const void* g, void* l) {
  __builtin_amdgcn_global_load_lds(
      (const __attribute__((address_space(1))) unsigned int*)g,
      (__attribute__((address_space(3))) unsigned int*)l, 16, 0, 0);
}
// 4-deep sorted-desc insert on tagged floats (max/min only)
__device__ __forceinline__ void kins4f(float (&S)[4], float v) {
#pragma unroll
  for (int p = 0; p < 4; ++p) {
    float mx = fmaxf(S[p], v);
    v = fminf(S[p], v);
    S[p] = mx;
  }
}
// merge two sorted-desc-4 float lists -> top-4 sorted desc (max/min network)
__device__ __forceinline__ void pmerge4f(float (&a)[4], const float (&b)[4]) {
  float c0 = fmaxf(a[0], b[3]), c1 = fmaxf(a[1], b[2]);
  float c2 = fmaxf(a[2], b[1]), c3 = fmaxf(a[3], b[0]);
  float t;
  t = fmaxf(c0, c2); c2 = fminf(c0, c2); c0 = t;
  t = fmaxf(c1, c3); c3 = fminf(c1, c3); c1 = t;
  t = fmaxf(c0, c1); c1 = fminf(c0, c1); c0 = t;
  t = fmaxf(c2, c3); c3 = fminf(c2, c3); c2 = t;
  a[0] = c0; a[1] = c1; a[2] = c2; a[3] = c3;
}

// ---------------- merged: corpus normalize+pack (blocks 0..49999) | q encode (50000..51023) ----------------
__global__ void prep_kernel(const float* __restrict__ corpus, unsigned short* __restrict__ Cpk,
                            const float* __restrict__ patient, const float* __restrict__ Wpe,
                            const float* __restrict__ bpe, double* __restrict__ q64,
                            unsigned short* __restrict__ Qpk) {
  __shared__ float ps[66];
  __shared__ double red[4];
  __shared__ double s_den;
  int tid = threadIdx.x;
  if (blockIdx.x < 50000) {
    int wid = tid >> 6, lane = tid & 63;
    int row = blockIdx.x * 4 + wid;
    if (row >= NCORPUS) return;
    const float4* p = (const float4*)(corpus + (size_t)row * 512);
    float4 a = p[lane * 2], b = p[lane * 2 + 1];
    float s = a.x * a.x + a.y * a.y + a.z * a.z + a.w * a.w +
              b.x * b.x + b.y * b.y + b.z * b.z + b.w * b.w;
    s = wave_sum_f32(s);
    float inv = 1.0f / fmaxf(sqrtf(s), 1e-12f);
    union { unsigned short us[8]; uint4 v; } pk;
    pk.us[0] = f2bf(a.x * inv); pk.us[1] = f2bf(a.y * inv);
    pk.us[2] = f2bf(a.z * inv); pk.us[3] = f2bf(a.w * inv);
    pk.us[4] = f2bf(b.x * inv); pk.us[5] = f2bf(b.y * inv);
    pk.us[6] = f2bf(b.z * inv); pk.us[7] = f2bf(b.w * inv);
    *(uint4*)(Cpk + (size_t)row * 512 + lane * 8) = pk.v;
  } else {
    int b = blockIdx.x - 50000;
    if (tid < 66) ps[tid] = patient[b * 66 + tid];
    __syncthreads();
    double v0 = (double)bpe[tid];
    double v1 = (double)bpe[tid + 256];
    for (int k = 0; k < 66; ++k) {
      double p = (double)ps[k];
      v0 += p * (double)Wpe[k * 512 + tid];
      v1 += p * (double)Wpe[k * 512 + tid + 256];
    }
    double ss = wave_sum_f64(v0 * v0 + v1 * v1);
    if ((tid & 63) == 0) red[tid >> 6] = ss;
    __syncthreads();
    if (tid == 0) s_den = fmax(sqrt(red[0] + red[1] + red[2] + red[3]), 1e-12);
    __syncthreads();
    double den = s_den;
    double o0 = v0 / den, o1 = v1 / den;
    q64[(size_t)b * 512 + tid] = o0;
    q64[(size_t)b * 512 + tid + 256] = o1;
    Qpk[(size_t)b * 512 + tid] = f2bf((float)o0);
    Qpk[(size_t)b * 512 + tid + 256] = f2bf((float)o1);
  }
}

// fold one sub's acc into tagged-float top-4 lists
template <bool CHECK>
__device__ __forceinline__ void fold_sub(f32x4 (&acc)[4][4], float (&lk)[4][4],
                                         int tagbase, int rb2) {
#pragma unroll
  for (int m = 0; m < 4; ++m)
#pragma unroll
    for (int j = 0; j < 4; ++j) {
      int mj = m * 16 + j;
      unsigned tg = (unsigned)(tagbase - mj);
      bool ok = true;
      if (CHECK) ok = (rb2 + mj) < NCORPUS;
#pragma unroll
      for (int n = 0; n < 4; ++n) {
        unsigned bb = (__float_as_uint(acc[m][n][j]) & 0xFFFFFC00u) | tg;
        float tf = __uint_as_float(bb);
        if (CHECK) tf = ok ? tf : NEGINF;
        kins4f(lk[n], tf);
      }
    }
}

// ---------------- sim^T GEMM via bf16 MFMA + tagged-float top-4 ----------------
__global__ __launch_bounds__(256, 2) void sim_topk_mfma(
    const unsigned short* __restrict__ Qpk, const unsigned short* __restrict__ Cpk,
    unsigned int* __restrict__ part_k) {
  __shared__ __align__(16) unsigned short smem[2][16384];  // [buf][As 8192 | Bs 8192] = 64 KiB

  int tid = threadIdx.x;
  int lane = tid & 63, wid = tid >> 6;
  int wr = wid >> 1, wc = wid & 1;
  int g = (blockIdx.x & 7) * NCHUNK + (blockIdx.x >> 3);
  int chunk = g >> 3, mt = g & 7;
  int m0 = mt * 128;
  int rbase = chunk * CHUNK;
  bool lastChunk = (rbase + CHUNK) > NCORPUS;

  int srow = tid >> 3;
  int scol = (((tid & 7) ^ (srow & 7)) << 3);

  int l15 = lane & 15, l4 = lane >> 4, l7 = lane & 7;
  int aoff[2][4], boff[2][4];
#pragma unroll
  for (int kk = 0; kk < 2; ++kk)
#pragma unroll
    for (int q = 0; q < 4; ++q) {
      int sw = (((kk * 4 + l4) ^ l7) << 3);
      aoff[kk][q] = (wr * 64 + q * 16 + l15) * 64 + sw;
      boff[kk][q] = 8192 + (wc * 64 + q * 16 + l15) * 64 + sw;
    }

  float lk[4][NPART];
#pragma unroll
  for (int n = 0; n < 4; ++n)
#pragma unroll
    for (int p = 0; p < NPART; ++p) lk[n][p] = NEGINF;

  f32x4 zero = {0.f, 0.f, 0.f, 0.f};
  f32x4 acc[4][4];
#pragma unroll
  for (int m = 0; m < 4; ++m)
#pragma unroll
    for (int n = 0; n < 4; ++n) acc[m][n] = zero;

  auto stageA = [&](int t, unsigned short* dst) {
    int sub = t >> 3, kt = t & 7;
    int rb = rbase + sub * 128;
    int k0 = kt * 64;
#pragma unroll
    for (int r = 0; r < 4; ++r) {
      int cr = rb + r * 32 + srow;
      if (cr > NCORPUS - 1) cr = NCORPUS - 1;
      gload16(Cpk + (size_t)cr * 512 + k0 + scol, dst + (r * 4 + wid) * 512);
    }
  };
  auto stageB = [&](int t, unsigned short* dst) {
    int kt = t & 7;
    int k0 = kt * 64;
#pragma unroll
    for (int r = 0; r < 4; ++r) {
      int qr = m0 + r * 32 + srow;
      gload16(Qpk + (size_t)qr * 512 + k0 + scol, dst + 8192 + (r * 4 + wid) * 512);
    }
  };

  stageA(0, smem[0]);
  stageB(0, smem[0]);

  for (int t = 0; t < NT; ++t) {
    int t1 = t + 1;
    if (t1 < NT) {
      unsigned short* nb = smem[t1 & 1];
      stageA(t1, nb);
      stageB(t1, nb);
      asm volatile("s_waitcnt vmcnt(8)" ::: "memory");
    } else {
      asm volatile("s_waitcnt vmcnt(0)" ::: "memory");
    }
    __builtin_amdgcn_s_barrier();
    const unsigned short* cb = smem[t & 1];
#pragma unroll
    for (int kk = 0; kk < 2; ++kk) {
      bf16x8 a[4], b[4];
#pragma unroll
      for (int m = 0; m < 4; ++m) a[m] = *(const bf16x8*)(cb + aoff[kk][m]);
#pragma unroll
      for (int n = 0; n < 4; ++n) b[n] = *(const bf16x8*)(cb + boff[kk][n]);
#pragma unroll
      for (int m = 0; m < 4; ++m)
#pragma unroll
        for (int n = 0; n < 4; ++n)
          acc[m][n] = __builtin_amdgcn_mfma_f32_16x16x32_bf16(a[m], b[n], acc[m][n], 0, 0, 0);
    }
    if ((t & 7) == 7) {
      int sub = t >> 3;
      int cellbase = sub * 128 + wr * 64 + l4 * 4;
      int rb2 = rbase + cellbase;
      int tagbase = (CHUNK - 1) - cellbase;
      if (lastChunk) fold_sub<true>(acc, lk, tagbase, rb2);
      else fold_sub<false>(acc, lk, tagbase, rb2);
#pragma unroll
      for (int m = 0; m < 4; ++m)
#pragma unroll
        for (int n = 0; n < 4; ++n) acc[m][n] = zero;
    }
    __builtin_amdgcn_s_barrier();
  }

#pragma unroll
  for (int rnd = 0; rnd < 2; ++rnd) {
    int msk = 16 << rnd;
#pragma unroll
    for (int n = 0; n < 4; ++n) {
      float ov[NPART];
#pragma unroll
      for (int p = 0; p < NPART; ++p) ov[p] = __shfl_xor(lk[n][p], msk, 64);
      pmerge4f(lk[n], ov);
    }
  }
  float* fb = (float*)&smem[0][0];
  if (wr == 1 && l4 == 0) {
#pragma unroll
    for (int n = 0; n < 4; ++n) {
      int col = wc * 64 + n * 16 + l15;
#pragma unroll
      for (int p = 0; p < NPART; ++p) fb[col * 4 + p] = lk[n][p];
    }
  }
  __syncthreads();
  if (wr == 0 && l4 == 0) {
#pragma unroll
    for (int n = 0; n < 4; ++n) {
      int col = wc * 64 + n * 16 + l15;
      float ov[NPART];
#pragma unroll
      for (int p = 0; p < NPART; ++p) ov[p] = fb[col * 4 + p];
      pmerge4f(lk[n], ov);
      size_t base = ((size_t)(m0 + col) * NCHUNK + chunk) * NPART;
#pragma unroll
      for (int p = 0; p < NPART; ++p) {
        unsigned bits = __float_as_uint(lk[n][p]);
        unsigned tag = bits & 0x3FFu;
        unsigned flip = bits ^ ((unsigned)((int)bits >> 31) | 0x80000000u);
        part_k[base + p] = (flip & 0xFFFFFC00u) | tag;
      }
    }
  }
}

// ---------------- merged: merge+refine (blocks 0..255) | tcenc+prop (256..1279) ----------------
__global__ __launch_bounds__(256, 2) void mr_tp_kernel(
    const unsigned int* __restrict__ part_k,
    const double* __restrict__ q64, const float* __restrict__ corpus,
    float* __restrict__ out_scores, float* __restrict__ out_idxf, int* __restrict__ topidx,
    const float* __restrict__ treatment, const float* __restrict__ conf,
    const float* __restrict__ Wte, const float* __restrict__ bte,
    const float* __restrict__ Wce, const float* __restrict__ bce,
    const float* __restrict__ Wp1, const float* __restrict__ bp1,
    const float* __restrict__ Wp2, const float* __restrict__ bp2,
    float* __restrict__ combined, float* __restrict__ out_prop) {
  __shared__ float cs[64];
  __shared__ float red0[4], red1[4];
  int tid = threadIdx.x;
  if (blockIdx.x < 256) {
    int wv = tid >> 6, lane = tid & 63;
    int row = blockIdx.x * 4 + wv;
    if (row >= BROWS) return;

    unsigned tk[16]; int tm[16];
#pragma unroll
    for (int p = 0; p < 16; ++p) { tk[p] = 0u; tm[p] = 0; }
    const unsigned* base = part_k + (size_t)row * (NCHUNK * NPART);
    for (int e = lane; e < NCHUNK * NPART; e += 64) {
      unsigned k = base[e];
      if (k > tk[15]) {
        unsigned kv = k; int mv = e;
#pragma unroll
        for (int p = 0; p < 16; ++p) {
          bool gt = kv > tk[p];
          unsigned ts = tk[p]; int ti = tm[p];
          tk[p] = gt ? kv : ts; tm[p] = gt ? mv : ti;
          kv = gt ? ts : kv;    mv = gt ? ti : mv;
        }
      }
    }
#pragma unroll
    for (int r = 0; r < 6; ++r) {
      unsigned ov[16]; int om[16];
#pragma unroll
      for (int p = 0; p < 16; ++p) {
        ov[p] = __shfl_xor(tk[p], 1 << r, 64);
        om[p] = __shfl_xor(tm[p], 1 << r, 64);
      }
      unsigned cv[16]; int cm[16];
#pragma unroll
      for (int i = 0; i < 16; ++i) {
        bool t = tk[i] >= ov[15 - i];
        cv[i] = t ? tk[i] : ov[15 - i];
        cm[i] = t ? tm[i] : om[15 - i];
      }
#pragma unroll
      for (int s = 8; s >= 1; s >>= 1)
#pragma unroll
        for (int bb = 0; bb < 16; bb += 2 * s)
#pragma unroll
          for (int o = 0; o < s; ++o) {
            int x = bb + o, y = bb + o + s;
            bool t = cv[x] >= cv[y];
            unsigned hv = t ? cv[x] : cv[y]; unsigned lv = t ? cv[y] : cv[x];
            int hm = t ? cm[x] : cm[y];      int lm = t ? cm[y] : cm[x];
            cv[x] = hv; cm[x] = hm; cv[y] = lv; cm[y] = lm;
          }
#pragma unroll
      for (int i = 0; i < 16; ++i) { tk[i] = cv[i]; tm[i] = cm[i]; }
    }
    int cidx[16];
#pragma unroll
    for (int c = 0; c < 16; ++c) {
      int ic = ((tm[c] >> 2) << 9) + (CHUNK - 1) - (int)(tk[c] & 0x3FFu);
      if (ic > NCORPUS - 1) ic = NCORPUS - 1;
      if (ic < 0) ic = 0;
      cidx[c] = ic;
    }
    double qv[8];
    const double* qrow = q64 + (size_t)row * 512;
#pragma unroll
    for (int t = 0; t < 8; ++t) qv[t] = qrow[lane * 8 + t];
    double rs[16];
#pragma unroll
    for (int c = 0; c < 16; ++c) {
      const float* crow = corpus + (size_t)cidx[c] * 512 + lane * 8;
      double qd = 0.0, cd = 0.0;
#pragma unroll
      for (int t = 0; t < 8; ++t) {
        double x = (double)crow[t];
        cd += x * x;
        qd += qv[t] * x;
      }
      qd = wave_sum_f64(qd);
      cd = wave_sum_f64(cd);
      rs[c] = qd / fmax(sqrt(cd), 1e-12);
    }
    if (lane == 0) {
      for (int o = 0; o < TOPK; ++o) {
        double bsc = -1e300;
        int bid2 = 0x7fffffff, bc = -1;
#pragma unroll
        for (int c = 0; c < 16; ++c) {
          bool better = (rs[c] > bsc) || (rs[c] == bsc && cidx[c] < bid2);
          if (better) { bsc = rs[c]; bid2 = cidx[c]; bc = c; }
        }
        out_scores[row * 8 + o] = (float)bsc;
        out_idxf[row * 8 + o] = (float)bid2;
        topidx[row * 8 + o] = bid2;
#pragma unroll
        for (int c = 0; c < 16; ++c)
          if (c == bc) rs[c] = -1e300;
      }
    }
  } else {
    int b = blockIdx.x - 256;
    if (tid < 64) cs[tid] = conf[b * 64 + tid];
    __syncthreads();
    float t0 = treatment[b * 2], t1 = treatment[b * 2 + 1];
    float l0 = 0.f, l1 = 0.f;
#pragma unroll
    for (int rep = 0; rep < 2; ++rep) {
      int h = tid + rep * 256;
      float te = fmaf(t0, Wte[h], fmaf(t1, Wte[512 + h], bte[h]));
      combined[(size_t)b * 1024 + h] = te;
      float ce = bce[h];
      float pv = bp1[h];
      for (int k = 0; k < 64; ++k) {
        float c = cs[k];
        ce = fmaf(c, Wce[k * 512 + h], ce);
        pv = fmaf(c, Wp1[k * 512 + h], pv);
      }
      combined[(size_t)b * 1024 + 512 + h] = ce;
      pv = fmaxf(pv, 0.f);
      l0 = fmaf(pv, Wp2[h * 2], l0);
      l1 = fmaf(pv, Wp2[h * 2 + 1], l1);
    }
    l0 = wave_sum_f32(l0);
    l1 = wave_sum_f32(l1);
    int wv = tid >> 6, lane = tid & 63;
    if (lane == 0) { red0[wv] = l0; red1[wv] = l1; }
    __syncthreads();
    if (tid == 0) {
      float a = red0[0] + red0[1] + red0[2] + red0[3] + bp2[0];
      float c2 = red1[0] + red1[1] + red1[2] + red1[3] + bp2[1];
      float m = fmaxf(a, c2);
      float e0 = expf(a - m), e1 = expf(c2 - m);
      float inv = 1.f / (e0 + e1);
      out_prop[b * 2] = e0 * inv;
      out_prop[b * 2 + 1] = e1 * inv;
    }
  }
}

// ---------------- 64x64 fp32 GEMM, 4x4/thread, async-staged dbuf ----------------
// MODE 0: A = gather(corpus rows via gidx), K split by 2 (by&1) -> C0/C1
// MODE 1: A = [combined(cols<1024) | p0+p1+abias], K split by 2 -> C0/C1
// MODE 2: A = relu(p0+p1+abias), no split, EPI bias+relu -> C0
template <int MODE, bool SPLIT, bool EPI>
__global__ __launch_bounds__(256, 2) void gemm64_kernel(
    const float* __restrict__ combined, const float* __restrict__ p0,
    const float* __restrict__ p1, const float* __restrict__ abias,
    const int* __restrict__ gidx, const float* __restrict__ corpus,
    const float* __restrict__ W, int ldw, const float* __restrict__ ebias,
    float* __restrict__ C0, float* __restrict__ C1, int ldc, int Kspan) {
  __shared__ float As[2][32 * 68];
  __shared__ float Bs[2][32 * 72];
  __shared__ int gi[512];
  int tid = threadIdx.x;
  int by = blockIdx.y;
  int m0, koff;
  float* Cout;
  if (SPLIT) {
    m0 = (by >> 1) * 64;
    int kh = by & 1;
    koff = kh * Kspan;
    Cout = kh ? C1 : C0;
  } else {
    m0 = by * 64;
    koff = 0;
    Cout = C0;
  }
  int n0 = blockIdx.x * 64;
  int nk = Kspan >> 5;

  if (MODE == 0) {
    gi[tid] = gidx[m0 * 8 + tid];
    gi[tid + 256] = gidx[m0 * 8 + tid + 256];
  }
  __syncthreads();

  // A granules: F = tid, tid+256 -> row=F>>3, fc=F&7 (k-local = fc*4)
  // B granules: F -> kb=F>>4, nf=F&15
  int arow0 = tid >> 3, afc0 = tid & 7;
  int arow1 = (tid + 256) >> 3, afc1 = (tid + 256) & 7;
  int bkb0 = tid >> 4, bnf0 = tid & 15;
  int bkb1 = (tid + 256) >> 4, bnf1 = (tid + 256) & 15;

  float4 aA[2], aB[2], aC[2];  // raw A sources (up to 3 per granule)
  float4 bB[2];

  auto loadA1 = [&](int row, int fc, int ks, float4& rA, float4& rB, float4& rC) {
    int kg = koff + ks * 32 + fc * 4;
    if (MODE == 0) {
      int r = gi[row * 8 + (kg >> 9)];
      rA = *(const float4*)(corpus + (size_t)r * 512 + (kg & 511));
    } else if (MODE == 1) {
      if (kg < 1024) {
        rA = *(const float4*)(combined + (size_t)(m0 + row) * 1024 + kg);
        rB = make_float4(0.f, 0.f, 0.f, 0.f);
        rC = make_float4(0.f, 0.f, 0.f, 0.f);
      } else {
        int e = kg - 1024;
        rA = *(const float4*)(p0 + (size_t)(m0 + row) * 512 + e);
        rB = *(const float4*)(p1 + (size_t)(m0 + row) * 512 + e);
        rC = *(const float4*)(abias + e);
      }
    } else {
      rA = *(const float4*)(p0 + (size_t)(m0 + row) * 512 + kg);
      rB = *(const float4*)(p1 + (size_t)(m0 + row) * 512 + kg);
      rC = *(const float4*)(abias + kg);
    }
  };
  auto loadB1 = [&](int kb, int nf, int ks) {
    int kg = koff + ks * 32 + kb;
    return *(const float4*)(W + (size_t)kg * ldw + n0 + nf * 4);
  };
  auto loadTile = [&](int ks) {
    loadA1(arow0, afc0, ks, aA[0], aB[0], aC[0]);
    loadA1(arow1, afc1, ks, aA[1], aB[1], aC[1]);
    bB[0] = loadB1(bkb0, bnf0, ks);
    bB[1] = loadB1(bkb1, bnf1, ks);
  };
  auto writeTile = [&](int buf) {
#pragma unroll
    for (int i = 0; i < 2; ++i) {
      int row = i ? arow1 : arow0;
      int fc = i ? afc1 : afc0;
      float4 v = aA[i];
      if (MODE == 1) {
        v.x += aB[i].x + aC[i].x; v.y += aB[i].y + aC[i].y;
        v.z += aB[i].z + aC[i].z; v.w += aB[i].w + aC[i].w;
      } else if (MODE == 2) {
        v.x = fmaxf(v.x + aB[i].x + aC[i].x, 0.f);
        v.y = fmaxf(v.y + aB[i].y + aC[i].y, 0.f);
        v.z = fmaxf(v.z + aB[i].z + aC[i].z, 0.f);
        v.w = fmaxf(v.w + aB[i].w + aC[i].w, 0.f);
      }
      float* d = As[buf] + (fc * 4) * 68 + row;
      d[0] = v.x; d[68] = v.y; d[136] = v.z; d[204] = v.w;
    }
    *(float4*)(Bs[buf] + bkb0 * 72 + bnf0 * 4) = bB[0];
    *(float4*)(Bs[buf] + bkb1 * 72 + bnf1 * 4) = bB[1];
  };

  float acc[4][4];
#pragma unroll
  for (int i = 0; i < 4; ++i)
#pragma unroll
    for (int j = 0; j < 4; ++j) acc[i][j] = 0.f;

  int tm = tid >> 4, tn = tid & 15;

  loadTile(0);
  writeTile(0);
  __syncthreads();
  for (int ks = 0; ks < nk; ++ks) {
    if (ks + 1 < nk) loadTile(ks + 1);   // issue early; hides under compute
    const float* as = As[ks & 1];
    const float* bs = Bs[ks & 1];
#pragma unroll
    for (int k = 0; k < 32; ++k) {
      float4 a4 = *(const float4*)(as + k * 68 + tm * 4);
      float4 b4 = *(const float4*)(bs + k * 72 + tn * 4);
      float av[4] = {a4.x, a4.y, a4.z, a4.w};
      float bv[4] = {b4.x, b4.y, b4.z, b4.w};
#pragma unroll
      for (int i = 0; i < 4; ++i)
#pragma unroll
        for (int j = 0; j < 4; ++j) acc[i][j] = fmaf(av[i], bv[j], acc[i][j]);
    }
    __syncthreads();
    if (ks + 1 < nk) {
      writeTile((ks + 1) & 1);
      __syncthreads();
    }
  }

  float4 eb = make_float4(0.f, 0.f, 0.f, 0.f);
  if (EPI) eb = *(const float4*)(ebias + n0 + tn * 4);
#pragma unroll
  for (int i = 0; i < 4; ++i) {
    float4 v;
    v.x = acc[i][0]; v.y = acc[i][1]; v.z = acc[i][2]; v.w = acc[i][3];
    if (EPI) {
      v.x = fmaxf(v.x + eb.x, 0.f); v.y = fmaxf(v.y + eb.y, 0.f);
      v.z = fmaxf(v.z + eb.z, 0.f); v.w = fmaxf(v.w + eb.w, 0.f);
    }
    *(float4*)(Cout + (size_t)(m0 + tm * 4 + i) * ldc + n0 + tn * 4) = v;
  }
}

// ---------------- outcome head (N=1) ----------------
__global__ void outcome_kernel(const float* __restrict__ h2, const float* __restrict__ Wo3,
                               const float* __restrict__ bo3, float* __restrict__ out) {
  int wv = threadIdx.x >> 6, lane = threadIdx.x & 63;
  int row = blockIdx.x * 4 + wv;
  if (row >= BROWS) return;
  float4 a = ((const float4*)(h2 + (size_t)row * 256))[lane];
  float4 w = ((const float4*)Wo3)[lane];
  float s = a.x * w.x + a.y * w.y + a.z * w.z + a.w * w.w;
  s = wave_sum_f32(s);
  if (lane == 0) out[row] = s + bo3[0];
}

extern "C" void kernel_launch(void* const* d_in, const int* in_sizes, int n_in,
                              void* d_out, int out_size, void* d_ws, size_t ws_size,
                              hipStream_t stream) {
  const float* treatment = (const float*)d_in[0];
  const float* conf = (const float*)d_in[1];
  const float* patient = (const float*)d_in[2];
  const float* corpus = (const float*)d_in[3];
  const float* Wpe = (const float*)d_in[4];
  const float* bpe = (const float*)d_in[5];
  const float* Wte = (const float*)d_in[6];
  const float* bte = (const float*)d_in[7];
  const float* Wce = (const float*)d_in[8];
  const float* bce = (const float*)d_in[9];
  const float* Wre = (const float*)d_in[10];
  const float* bre = (const float*)d_in[11];
  const float* Wo1 = (const float*)d_in[12];
  const float* bo1 = (const float*)d_in[13];
  const float* Wo2 = (const float*)d_in[14];
  const float* bo2 = (const float*)d_in[15];
  const float* Wo3 = (const float*)d_in[16];
  const float* bo3 = (const float*)d_in[17];
  const float* Wp1 = (const float*)d_in[18];
  const float* bp1 = (const float*)d_in[19];
  const float* Wp2 = (const float*)d_in[20];
  const float* bp2 = (const float*)d_in[21];

  float* out = (float*)d_out;
  float* out_outcome = out;                       // [1024]
  float* out_scores = out + 1024;                 // [1024*8]
  float* out_idxf = out + 1024 + 8192;            // [1024*8] (ints as float)
  float* out_prop = out + 1024 + 8192 + 8192;     // [1024*2]

  char* ws = (char*)d_ws;
  size_t off = 0;
  auto carve = [&](size_t bytes) {
    void* p = ws + off;
    off = (off + bytes + 255) & ~(size_t)255;
    return p;
  };
  double* q64 = (double*)carve((size_t)1024 * 512 * 8);
  unsigned short* Qpk = (unsigned short*)carve((size_t)1024 * 512 * 2);
  unsigned short* Cpk = (unsigned short*)carve((size_t)NCORPUS * 512 * 2);
  unsigned int* part_k = (unsigned int*)carve((size_t)1024 * NCHUNK * NPART * 4);
  int* topidx = (int*)carve((size_t)1024 * 8 * 4);
  float* combined = (float*)carve((size_t)1024 * 1024 * 4);   // [t_enc | c_enc]
  float* p0 = (float*)carve((size_t)1024 * 512 * 4);          // r_enc partial K-half 0
  float* p1 = (float*)carve((size_t)1024 * 512 * 4);          // r_enc partial K-half 1
  float* pp0 = (float*)carve((size_t)1024 * 512 * 4);         // h1 partial K-half 0
  float* pp1 = (float*)carve((size_t)1024 * 512 * 4);         // h1 partial K-half 1
  float* h2 = (float*)carve((size_t)1024 * 256 * 4);

  prep_kernel<<<dim3(51024), dim3(256), 0, stream>>>(corpus, Cpk, patient, Wpe, bpe, q64, Qpk);
  sim_topk_mfma<<<dim3(8 * NCHUNK), dim3(256), 0, stream>>>(Qpk, Cpk, part_k);
  mr_tp_kernel<<<dim3(1280), dim3(256), 0, stream>>>(part_k, q64, corpus,
                                                     out_scores, out_idxf, topidx,
                                                     treatment, conf, Wte, bte, Wce, bce,
                                                     Wp1, bp1, Wp2, bp2, combined, out_prop);
  // r_enc = gather(corpus) @ Wre, K=4096 split 2x2048 -> p0,p1 (bre folded downstream)
  gemm64_kernel<0, true, false><<<dim3(8, 32), dim3(256), 0, stream>>>(
      (const float*)nullptr, (const float*)nullptr, (const float*)nullptr, (const float*)nullptr,
      topidx, corpus, Wre, 512, (const float*)nullptr, p0, p1, 512, 2048);
  // h1 = [combined | p0+p1+bre] @ Wo1, K=1536 split 2x768 -> pp0,pp1 (bo1+relu folded downstream)
  gemm64_kernel<1, true, false><<<dim3(8, 32), dim3(256), 0, stream>>>(
      combined, p0, p1, bre, (const int*)nullptr, (const float*)nullptr,
      Wo1, 512, (const float*)nullptr, pp0, pp1, 512, 768);
  // h2 = relu(relu(pp0+pp1+bo1) @ Wo2 + bo2), K=512
  gemm64_kernel<2, false, true><<<dim3(4, 16), dim3(256), 0, stream>>>(
      (const float*)nullptr, pp0, pp1, bo1, (const int*)nullptr, (const float*)nullptr,
      Wo2, 256, bo2, h2, (float*)nullptr, 256, 512);
  outcome_kernel<<<dim3(256), dim3(256), 0, stream>>>(h2, Wo3, bo3, out_outcome);
}

// Round 13
// 635.588 us; speedup vs baseline: 1.5126x; 1.5126x over previous
//
#include <hip/hip_runtime.h>
#include <math.h>

#define TOPK 8
#define NCORPUS 200000
#define BROWS 1024
#define CHUNK 512
#define NCHUNK 391           /* ceil(200000/512) */
#define NT 32                /* 4 subs * 8 K-steps (BK=64) */
#define NPART 4              /* per-chunk candidate depth */
#define NEGINF (-3.0e38f)

typedef __attribute__((ext_vector_type(8))) short bf16x8;
typedef __attribute__((ext_vector_type(4))) float f32x4;

__device__ __forceinline__ float wave_sum_f32(float v) {
#pragma unroll
  for (int m = 32; m >= 1; m >>= 1) v += __shfl_xor(v, m, 64);
  return v;
}
__device__ __forceinline__ double wave_sum_f64(double v) {
#pragma unroll
  for (int m = 32; m >= 1; m >>= 1) v += __shfl_xor(v, m, 64);
  return v;
}
__device__ __forceinline__ unsigned short f2bf(float f) {
  unsigned int u = __float_as_uint(f);
  unsigned int r = (u + 0x7fffu + ((u >> 16) & 1u)) >> 16;
  return (unsigned short)r;
}
__device__ __forceinline__ void gload16(const void* g, void* l) {
  __builtin_amdgcn_global_load_lds(
      (const __attribute__((address_space(1))) unsigned int*)g,
      (__attribute__((address_space(3))) unsigned int*)l, 16, 0, 0);
}
// 4-deep sorted-desc insert on tagged floats (max/min only)
__device__ __forceinline__ void kins4f(float (&S)[4], float v) {
#pragma unroll
  for (int p = 0; p < 4; ++p) {
    float mx = fmaxf(S[p], v);
    v = fminf(S[p], v);
    S[p] = mx;
  }
}
// merge two sorted-desc-4 float lists -> top-4 sorted desc (max/min network)
__device__ __forceinline__ void pmerge4f(float (&a)[4], const float (&b)[4]) {
  float c0 = fmaxf(a[0], b[3]), c1 = fmaxf(a[1], b[2]);
  float c2 = fmaxf(a[2], b[1]), c3 = fmaxf(a[3], b[0]);
  float t;
  t = fmaxf(c0, c2); c2 = fminf(c0, c2); c0 = t;
  t = fmaxf(c1, c3); c3 = fminf(c1, c3); c1 = t;
  t = fmaxf(c0, c1); c1 = fminf(c0, c1); c0 = t;
  t = fmaxf(c2, c3); c3 = fminf(c2, c3); c2 = t;
  a[0] = c0; a[1] = c1; a[2] = c2; a[3] = c3;
}

// ---------------- merged: corpus normalize+pack (blocks 0..49999) | q encode (50000..51023) ----------------
__global__ void prep_kernel(const float* __restrict__ corpus, unsigned short* __restrict__ Cpk,
                            const float* __restrict__ patient, const float* __restrict__ Wpe,
                            const float* __restrict__ bpe, double* __restrict__ q64,
                            unsigned short* __restrict__ Qpk) {
  __shared__ float ps[66];
  __shared__ double red[4];
  __shared__ double s_den;
  int tid = threadIdx.x;
  if (blockIdx.x < 50000) {
    int wid = tid >> 6, lane = tid & 63;
    int row = blockIdx.x * 4 + wid;
    if (row >= NCORPUS) return;
    const float4* p = (const float4*)(corpus + (size_t)row * 512);
    float4 a = p[lane * 2], b = p[lane * 2 + 1];
    float s = a.x * a.x + a.y * a.y + a.z * a.z + a.w * a.w +
              b.x * b.x + b.y * b.y + b.z * b.z + b.w * b.w;
    s = wave_sum_f32(s);
    float inv = 1.0f / fmaxf(sqrtf(s), 1e-12f);
    union { unsigned short us[8]; uint4 v; } pk;
    pk.us[0] = f2bf(a.x * inv); pk.us[1] = f2bf(a.y * inv);
    pk.us[2] = f2bf(a.z * inv); pk.us[3] = f2bf(a.w * inv);
    pk.us[4] = f2bf(b.x * inv); pk.us[5] = f2bf(b.y * inv);
    pk.us[6] = f2bf(b.z * inv); pk.us[7] = f2bf(b.w * inv);
    *(uint4*)(Cpk + (size_t)row * 512 + lane * 8) = pk.v;
  } else {
    int b = blockIdx.x - 50000;
    if (tid < 66) ps[tid] = patient[b * 66 + tid];
    __syncthreads();
    double v0 = (double)bpe[tid];
    double v1 = (double)bpe[tid + 256];
    for (int k = 0; k < 66; ++k) {
      double p = (double)ps[k];
      v0 += p * (double)Wpe[k * 512 + tid];
      v1 += p * (double)Wpe[k * 512 + tid + 256];
    }
    double ss = wave_sum_f64(v0 * v0 + v1 * v1);
    if ((tid & 63) == 0) red[tid >> 6] = ss;
    __syncthreads();
    if (tid == 0) s_den = fmax(sqrt(red[0] + red[1] + red[2] + red[3]), 1e-12);
    __syncthreads();
    double den = s_den;
    double o0 = v0 / den, o1 = v1 / den;
    q64[(size_t)b * 512 + tid] = o0;
    q64[(size_t)b * 512 + tid + 256] = o1;
    Qpk[(size_t)b * 512 + tid] = f2bf((float)o0);
    Qpk[(size_t)b * 512 + tid + 256] = f2bf((float)o1);
  }
}

// fold one sub's acc into tagged-float top-4 lists
template <bool CHECK>
__device__ __forceinline__ void fold_sub(f32x4 (&acc)[4][4], float (&lk)[4][4],
                                         int tagbase, int rb2) {
#pragma unroll
  for (int m = 0; m < 4; ++m)
#pragma unroll
    for (int j = 0; j < 4; ++j) {
      int mj = m * 16 + j;
      unsigned tg = (unsigned)(tagbase - mj);
      bool ok = true;
      if (CHECK) ok = (rb2 + mj) < NCORPUS;
#pragma unroll
      for (int n = 0; n < 4; ++n) {
        unsigned bb = (__float_as_uint(acc[m][n][j]) & 0xFFFFFC00u) | tg;
        float tf = __uint_as_float(bb);
        if (CHECK) tf = ok ? tf : NEGINF;
        kins4f(lk[n], tf);
      }
    }
}

// ---------------- sim^T GEMM via bf16 MFMA + tagged-float top-4 ----------------
__global__ __launch_bounds__(256, 2) void sim_topk_mfma(
    const unsigned short* __restrict__ Qpk, const unsigned short* __restrict__ Cpk,
    unsigned int* __restrict__ part_k) {
  __shared__ __align__(16) unsigned short smem[2][16384];  // [buf][As 8192 | Bs 8192] = 64 KiB

  int tid = threadIdx.x;
  int lane = tid & 63, wid = tid >> 6;
  int wr = wid >> 1, wc = wid & 1;
  int g = (blockIdx.x & 7) * NCHUNK + (blockIdx.x >> 3);
  int chunk = g >> 3, mt = g & 7;
  int m0 = mt * 128;
  int rbase = chunk * CHUNK;
  bool lastChunk = (rbase + CHUNK) > NCORPUS;

  int srow = tid >> 3;
  int scol = (((tid & 7) ^ (srow & 7)) << 3);

  int l15 = lane & 15, l4 = lane >> 4, l7 = lane & 7;
  int aoff[2][4], boff[2][4];
#pragma unroll
  for (int kk = 0; kk < 2; ++kk)
#pragma unroll
    for (int q = 0; q < 4; ++q) {
      int sw = (((kk * 4 + l4) ^ l7) << 3);
      aoff[kk][q] = (wr * 64 + q * 16 + l15) * 64 + sw;
      boff[kk][q] = 8192 + (wc * 64 + q * 16 + l15) * 64 + sw;
    }

  float lk[4][NPART];
#pragma unroll
  for (int n = 0; n < 4; ++n)
#pragma unroll
    for (int p = 0; p < NPART; ++p) lk[n][p] = NEGINF;

  f32x4 zero = {0.f, 0.f, 0.f, 0.f};
  f32x4 acc[4][4];
#pragma unroll
  for (int m = 0; m < 4; ++m)
#pragma unroll
    for (int n = 0; n < 4; ++n) acc[m][n] = zero;

  auto stageA = [&](int t, unsigned short* dst) {
    int sub = t >> 3, kt = t & 7;
    int rb = rbase + sub * 128;
    int k0 = kt * 64;
#pragma unroll
    for (int r = 0; r < 4; ++r) {
      int cr = rb + r * 32 + srow;
      if (cr > NCORPUS - 1) cr = NCORPUS - 1;
      gload16(Cpk + (size_t)cr * 512 + k0 + scol, dst + (r * 4 + wid) * 512);
    }
  };
  auto stageB = [&](int t, unsigned short* dst) {
    int kt = t & 7;
    int k0 = kt * 64;
#pragma unroll
    for (int r = 0; r < 4; ++r) {
      int qr = m0 + r * 32 + srow;
      gload16(Qpk + (size_t)qr * 512 + k0 + scol, dst + 8192 + (r * 4 + wid) * 512);
    }
  };

  stageA(0, smem[0]);
  stageB(0, smem[0]);

  for (int t = 0; t < NT; ++t) {
    int t1 = t + 1;
    if (t1 < NT) {
      unsigned short* nb = smem[t1 & 1];
      stageA(t1, nb);
      stageB(t1, nb);
      asm volatile("s_waitcnt vmcnt(8)" ::: "memory");
    } else {
      asm volatile("s_waitcnt vmcnt(0)" ::: "memory");
    }
    __builtin_amdgcn_s_barrier();
    const unsigned short* cb = smem[t & 1];
#pragma unroll
    for (int kk = 0; kk < 2; ++kk) {
      bf16x8 a[4], b[4];
#pragma unroll
      for (int m = 0; m < 4; ++m) a[m] = *(const bf16x8*)(cb + aoff[kk][m]);
#pragma unroll
      for (int n = 0; n < 4; ++n) b[n] = *(const bf16x8*)(cb + boff[kk][n]);
#pragma unroll
      for (int m = 0; m < 4; ++m)
#pragma unroll
        for (int n = 0; n < 4; ++n)
          acc[m][n] = __builtin_amdgcn_mfma_f32_16x16x32_bf16(a[m], b[n], acc[m][n], 0, 0, 0);
    }
    if ((t & 7) == 7) {
      int sub = t >> 3;
      int cellbase = sub * 128 + wr * 64 + l4 * 4;
      int rb2 = rbase + cellbase;
      int tagbase = (CHUNK - 1) - cellbase;
      if (lastChunk) fold_sub<true>(acc, lk, tagbase, rb2);
      else fold_sub<false>(acc, lk, tagbase, rb2);
#pragma unroll
      for (int m = 0; m < 4; ++m)
#pragma unroll
        for (int n = 0; n < 4; ++n) acc[m][n] = zero;
    }
    __builtin_amdgcn_s_barrier();
  }

#pragma unroll
  for (int rnd = 0; rnd < 2; ++rnd) {
    int msk = 16 << rnd;
#pragma unroll
    for (int n = 0; n < 4; ++n) {
      float ov[NPART];
#pragma unroll
      for (int p = 0; p < NPART; ++p) ov[p] = __shfl_xor(lk[n][p], msk, 64);
      pmerge4f(lk[n], ov);
    }
  }
  float* fb = (float*)&smem[0][0];
  if (wr == 1 && l4 == 0) {
#pragma unroll
    for (int n = 0; n < 4; ++n) {
      int col = wc * 64 + n * 16 + l15;
#pragma unroll
      for (int p = 0; p < NPART; ++p) fb[col * 4 + p] = lk[n][p];
    }
  }
  __syncthreads();
  if (wr == 0 && l4 == 0) {
#pragma unroll
    for (int n = 0; n < 4; ++n) {
      int col = wc * 64 + n * 16 + l15;
      float ov[NPART];
#pragma unroll
      for (int p = 0; p < NPART; ++p) ov[p] = fb[col * 4 + p];
      pmerge4f(lk[n], ov);
      size_t base = ((size_t)(m0 + col) * NCHUNK + chunk) * NPART;
#pragma unroll
      for (int p = 0; p < NPART; ++p) {
        unsigned bits = __float_as_uint(lk[n][p]);
        unsigned tag = bits & 0x3FFu;
        unsigned flip = bits ^ ((unsigned)((int)bits >> 31) | 0x80000000u);
        part_k[base + p] = (flip & 0xFFFFFC00u) | tag;
      }
    }
  }
}

// ---------------- merged: merge+refine (blocks 0..255) | tcenc+prop (256..1279) ----------------
__global__ __launch_bounds__(256, 2) void mr_tp_kernel(
    const unsigned int* __restrict__ part_k,
    const double* __restrict__ q64, const float* __restrict__ corpus,
    float* __restrict__ out_scores, float* __restrict__ out_idxf, int* __restrict__ topidx,
    const float* __restrict__ treatment, const float* __restrict__ conf,
    const float* __restrict__ Wte, const float* __restrict__ bte,
    const float* __restrict__ Wce, const float* __restrict__ bce,
    const float* __restrict__ Wp1, const float* __restrict__ bp1,
    const float* __restrict__ Wp2, const float* __restrict__ bp2,
    float* __restrict__ combined, float* __restrict__ out_prop) {
  __shared__ float cs[64];
  __shared__ float red0[4], red1[4];
  int tid = threadIdx.x;
  if (blockIdx.x < 256) {
    int wv = tid >> 6, lane = tid & 63;
    int row = blockIdx.x * 4 + wv;
    if (row >= BROWS) return;

    unsigned tk[16]; int tm[16];
#pragma unroll
    for (int p = 0; p < 16; ++p) { tk[p] = 0u; tm[p] = 0; }
    const unsigned* base = part_k + (size_t)row * (NCHUNK * NPART);
    for (int e = lane; e < NCHUNK * NPART; e += 64) {
      unsigned k = base[e];
      if (k > tk[15]) {
        unsigned kv = k; int mv = e;
#pragma unroll
        for (int p = 0; p < 16; ++p) {
          bool gt = kv > tk[p];
          unsigned ts = tk[p]; int ti = tm[p];
          tk[p] = gt ? kv : ts; tm[p] = gt ? mv : ti;
          kv = gt ? ts : kv;    mv = gt ? ti : mv;
        }
      }
    }
#pragma unroll
    for (int r = 0; r < 6; ++r) {
      unsigned ov[16]; int om[16];
#pragma unroll
      for (int p = 0; p < 16; ++p) {
        ov[p] = __shfl_xor(tk[p], 1 << r, 64);
        om[p] = __shfl_xor(tm[p], 1 << r, 64);
      }
      unsigned cv[16]; int cm[16];
#pragma unroll
      for (int i = 0; i < 16; ++i) {
        bool t = tk[i] >= ov[15 - i];
        cv[i] = t ? tk[i] : ov[15 - i];
        cm[i] = t ? tm[i] : om[15 - i];
      }
#pragma unroll
      for (int s = 8; s >= 1; s >>= 1)
#pragma unroll
        for (int bb = 0; bb < 16; bb += 2 * s)
#pragma unroll
          for (int o = 0; o < s; ++o) {
            int x = bb + o, y = bb + o + s;
            bool t = cv[x] >= cv[y];
            unsigned hv = t ? cv[x] : cv[y]; unsigned lv = t ? cv[y] : cv[x];
            int hm = t ? cm[x] : cm[y];      int lm = t ? cm[y] : cm[x];
            cv[x] = hv; cm[x] = hm; cv[y] = lv; cm[y] = lm;
          }
#pragma unroll
      for (int i = 0; i < 16; ++i) { tk[i] = cv[i]; tm[i] = cm[i]; }
    }
    int cidx[16];
#pragma unroll
    for (int c = 0; c < 16; ++c) {
      int ic = ((tm[c] >> 2) << 9) + (CHUNK - 1) - (int)(tk[c] & 0x3FFu);
      if (ic > NCORPUS - 1) ic = NCORPUS - 1;
      if (ic < 0) ic = 0;
      cidx[c] = ic;
    }
    double qv[8];
    const double* qrow = q64 + (size_t)row * 512;
#pragma unroll
    for (int t = 0; t < 8; ++t) qv[t] = qrow[lane * 8 + t];
    double rs[16];
#pragma unroll
    for (int c = 0; c < 16; ++c) {
      const float* crow = corpus + (size_t)cidx[c] * 512 + lane * 8;
      double qd = 0.0, cd = 0.0;
#pragma unroll
      for (int t = 0; t < 8; ++t) {
        double x = (double)crow[t];
        cd += x * x;
        qd += qv[t] * x;
      }
      qd = wave_sum_f64(qd);
      cd = wave_sum_f64(cd);
      rs[c] = qd / fmax(sqrt(cd), 1e-12);
    }
    if (lane == 0) {
      for (int o = 0; o < TOPK; ++o) {
        double bsc = -1e300;
        int bid2 = 0x7fffffff, bc = -1;
#pragma unroll
        for (int c = 0; c < 16; ++c) {
          bool better = (rs[c] > bsc) || (rs[c] == bsc && cidx[c] < bid2);
          if (better) { bsc = rs[c]; bid2 = cidx[c]; bc = c; }
        }
        out_scores[row * 8 + o] = (float)bsc;
        out_idxf[row * 8 + o] = (float)bid2;
        topidx[row * 8 + o] = bid2;
#pragma unroll
        for (int c = 0; c < 16; ++c)
          if (c == bc) rs[c] = -1e300;
      }
    }
  } else {
    int b = blockIdx.x - 256;
    if (tid < 64) cs[tid] = conf[b * 64 + tid];
    __syncthreads();
    float t0 = treatment[b * 2], t1 = treatment[b * 2 + 1];
    float l0 = 0.f, l1 = 0.f;
#pragma unroll
    for (int rep = 0; rep < 2; ++rep) {
      int h = tid + rep * 256;
      float te = fmaf(t0, Wte[h], fmaf(t1, Wte[512 + h], bte[h]));
      combined[(size_t)b * 1024 + h] = te;
      float ce = bce[h];
      float pv = bp1[h];
      for (int k = 0; k < 64; ++k) {
        float c = cs[k];
        ce = fmaf(c, Wce[k * 512 + h], ce);
        pv = fmaf(c, Wp1[k * 512 + h], pv);
      }
      combined[(size_t)b * 1024 + 512 + h] = ce;
      pv = fmaxf(pv, 0.f);
      l0 = fmaf(pv, Wp2[h * 2], l0);
      l1 = fmaf(pv, Wp2[h * 2 + 1], l1);
    }
    l0 = wave_sum_f32(l0);
    l1 = wave_sum_f32(l1);
    int wv = tid >> 6, lane = tid & 63;
    if (lane == 0) { red0[wv] = l0; red1[wv] = l1; }
    __syncthreads();
    if (tid == 0) {
      float a = red0[0] + red0[1] + red0[2] + red0[3] + bp2[0];
      float c2 = red1[0] + red1[1] + red1[2] + red1[3] + bp2[1];
      float m = fmaxf(a, c2);
      float e0 = expf(a - m), e1 = expf(c2 - m);
      float inv = 1.f / (e0 + e1);
      out_prop[b * 2] = e0 * inv;
      out_prop[b * 2 + 1] = e1 * inv;
    }
  }
}

// ---------------- 64x64 fp32 GEMM, 4x4/thread, immediate-write staged dbuf ----------------
// MODE 0: A = gather(corpus rows via gidx), K split by 2 (by&1) -> C0/C1
// MODE 1: A = [combined(cols<1024) | p0+p1+abias], K split by 2 -> C0/C1
// MODE 2: A = relu(p0+p1+abias), no split, EPI bias+relu -> C0
template <int MODE, bool SPLIT, bool EPI>
__global__ __launch_bounds__(256, 2) void gemm64_kernel(
    const float* __restrict__ combined, const float* __restrict__ p0,
    const float* __restrict__ p1, const float* __restrict__ abias,
    const int* __restrict__ gidx, const float* __restrict__ corpus,
    const float* __restrict__ W, int ldw, const float* __restrict__ ebias,
    float* __restrict__ C0, float* __restrict__ C1, int ldc, int Kspan) {
  __shared__ float As[2][32 * 68];   // [k][row] transposed, pitch 68 (272 B, 16B-aligned)
  __shared__ float Bs[2][32 * 72];   // [k][n], pitch 72 (288 B)
  __shared__ int gi[512];
  int tid = threadIdx.x;
  int by = blockIdx.y;
  int m0, koff;
  float* Cout;
  if (SPLIT) {
    m0 = (by >> 1) * 64;
    int kh = by & 1;
    koff = kh * Kspan;
    Cout = kh ? C1 : C0;
  } else {
    m0 = by * 64;
    koff = 0;
    Cout = C0;
  }
  int n0 = blockIdx.x * 64;
  int nk = Kspan >> 5;

  if (MODE == 0) {
    gi[tid] = gidx[m0 * 8 + tid];
    gi[tid + 256] = gidx[m0 * 8 + tid + 256];
    __syncthreads();
  }

  // A granules: (row, fc) — granule covers k-local [fc*4, fc*4+4); two per thread
  int arow0 = tid >> 3, afc = tid & 7;
  int arow1 = arow0 + 32;
  // B granules: (kb, nf); two per thread
  int bkb0 = tid >> 4, bnf = tid & 15;
  int bkb1 = bkb0 + 16;

  auto stageA1 = [&](int row, int ks, int buf) {
    int kg = koff + ks * 32 + afc * 4;
    float4 v;
    if (MODE == 0) {
      int r = gi[row * 8 + (kg >> 9)];
      v = *(const float4*)(corpus + (size_t)r * 512 + (kg & 511));
    } else if (MODE == 1) {
      if (kg < 1024) {
        v = *(const float4*)(combined + (size_t)(m0 + row) * 1024 + kg);
      } else {
        int e = kg - 1024;
        float4 x = *(const float4*)(p0 + (size_t)(m0 + row) * 512 + e);
        float4 y = *(const float4*)(p1 + (size_t)(m0 + row) * 512 + e);
        float4 z = *(const float4*)(abias + e);
        v.x = x.x + y.x + z.x; v.y = x.y + y.y + z.y;
        v.z = x.z + y.z + z.z; v.w = x.w + y.w + z.w;
      }
    } else {
      float4 x = *(const float4*)(p0 + (size_t)(m0 + row) * 512 + kg);
      float4 y = *(const float4*)(p1 + (size_t)(m0 + row) * 512 + kg);
      float4 z = *(const float4*)(abias + kg);
      v.x = fmaxf(x.x + y.x + z.x, 0.f); v.y = fmaxf(x.y + y.y + z.y, 0.f);
      v.z = fmaxf(x.z + y.z + z.z, 0.f); v.w = fmaxf(x.w + y.w + z.w, 0.f);
    }
    float* d = As[buf] + (afc * 4) * 68 + row;
    d[0] = v.x; d[68] = v.y; d[136] = v.z; d[204] = v.w;
  };
  auto stage = [&](int ks, int buf) {
    stageA1(arow0, ks, buf);
    stageA1(arow1, ks, buf);
    int kg0 = koff + ks * 32 + bkb0;
    *(float4*)(Bs[buf] + bkb0 * 72 + bnf * 4) =
        *(const float4*)(W + (size_t)kg0 * ldw + n0 + bnf * 4);
    int kg1 = koff + ks * 32 + bkb1;
    *(float4*)(Bs[buf] + bkb1 * 72 + bnf * 4) =
        *(const float4*)(W + (size_t)kg1 * ldw + n0 + bnf * 4);
  };

  float acc[4][4];
#pragma unroll
  for (int i = 0; i < 4; ++i)
#pragma unroll
    for (int j = 0; j < 4; ++j) acc[i][j] = 0.f;

  int tm = tid >> 4, tn = tid & 15;

  stage(0, 0);
  __syncthreads();
  for (int ks = 0; ks < nk; ++ks) {
    if (ks + 1 < nk) stage(ks + 1, (ks + 1) & 1);   // load+write buf^1 while computing buf
    const float* as = As[ks & 1];
    const float* bs = Bs[ks & 1];
#pragma unroll
    for (int k = 0; k < 32; ++k) {
      float4 a4 = *(const float4*)(as + k * 68 + tm * 4);
      float4 b4 = *(const float4*)(bs + k * 72 + tn * 4);
      float av[4] = {a4.x, a4.y, a4.z, a4.w};
      float bv[4] = {b4.x, b4.y, b4.z, b4.w};
#pragma unroll
      for (int i = 0; i < 4; ++i)
#pragma unroll
        for (int j = 0; j < 4; ++j) acc[i][j] = fmaf(av[i], bv[j], acc[i][j]);
    }
    __syncthreads();
  }

  float4 eb = make_float4(0.f, 0.f, 0.f, 0.f);
  if (EPI) eb = *(const float4*)(ebias + n0 + tn * 4);
#pragma unroll
  for (int i = 0; i < 4; ++i) {
    float4 v;
    v.x = acc[i][0]; v.y = acc[i][1]; v.z = acc[i][2]; v.w = acc[i][3];
    if (EPI) {
      v.x = fmaxf(v.x + eb.x, 0.f); v.y = fmaxf(v.y + eb.y, 0.f);
      v.z = fmaxf(v.z + eb.z, 0.f); v.w = fmaxf(v.w + eb.w, 0.f);
    }
    *(float4*)(Cout + (size_t)(m0 + tm * 4 + i) * ldc + n0 + tn * 4) = v;
  }
}

// ---------------- outcome head (N=1) ----------------
__global__ void outcome_kernel(const float* __restrict__ h2, const float* __restrict__ Wo3,
                               const float* __restrict__ bo3, float* __restrict__ out) {
  int wv = threadIdx.x >> 6, lane = threadIdx.x & 63;
  int row = blockIdx.x * 4 + wv;
  if (row >= BROWS) return;
  float4 a = ((const float4*)(h2 + (size_t)row * 256))[lane];
  float4 w = ((const float4*)Wo3)[lane];
  float s = a.x * w.x + a.y * w.y + a.z * w.z + a.w * w.w;
  s = wave_sum_f32(s);
  if (lane == 0) out[row] = s + bo3[0];
}

extern "C" void kernel_launch(void* const* d_in, const int* in_sizes, int n_in,
                              void* d_out, int out_size, void* d_ws, size_t ws_size,
                              hipStream_t stream) {
  const float* treatment = (const float*)d_in[0];
  const float* conf = (const float*)d_in[1];
  const float* patient = (const float*)d_in[2];
  const float* corpus = (const float*)d_in[3];
  const float* Wpe = (const float*)d_in[4];
  const float* bpe = (const float*)d_in[5];
  const float* Wte = (const float*)d_in[6];
  const float* bte = (const float*)d_in[7];
  const float* Wce = (const float*)d_in[8];
  const float* bce = (const float*)d_in[9];
  const float* Wre = (const float*)d_in[10];
  const float* bre = (const float*)d_in[11];
  const float* Wo1 = (const float*)d_in[12];
  const float* bo1 = (const float*)d_in[13];
  const float* Wo2 = (const float*)d_in[14];
  const float* bo2 = (const float*)d_in[15];
  const float* Wo3 = (const float*)d_in[16];
  const float* bo3 = (const float*)d_in[17];
  const float* Wp1 = (const float*)d_in[18];
  const float* bp1 = (const float*)d_in[19];
  const float* Wp2 = (const float*)d_in[20];
  const float* bp2 = (const float*)d_in[21];

  float* out = (float*)d_out;
  float* out_outcome = out;                       // [1024]
  float* out_scores = out + 1024;                 // [1024*8]
  float* out_idxf = out + 1024 + 8192;            // [1024*8] (ints as float)
  float* out_prop = out + 1024 + 8192 + 8192;     // [1024*2]

  char* ws = (char*)d_ws;
  size_t off = 0;
  auto carve = [&](size_t bytes) {
    void* p = ws + off;
    off = (off + bytes + 255) & ~(size_t)255;
    return p;
  };
  double* q64 = (double*)carve((size_t)1024 * 512 * 8);
  unsigned short* Qpk = (unsigned short*)carve((size_t)1024 * 512 * 2);
  unsigned short* Cpk = (unsigned short*)carve((size_t)NCORPUS * 512 * 2);
  unsigned int* part_k = (unsigned int*)carve((size_t)1024 * NCHUNK * NPART * 4);
  int* topidx = (int*)carve((size_t)1024 * 8 * 4);
  float* combined = (float*)carve((size_t)1024 * 1024 * 4);   // [t_enc | c_enc]
  float* p0 = (float*)carve((size_t)1024 * 512 * 4);          // r_enc partial K-half 0
  float* p1 = (float*)carve((size_t)1024 * 512 * 4);          // r_enc partial K-half 1
  float* pp0 = (float*)carve((size_t)1024 * 512 * 4);         // h1 partial K-half 0
  float* pp1 = (float*)carve((size_t)1024 * 512 * 4);         // h1 partial K-half 1
  float* h2 = (float*)carve((size_t)1024 * 256 * 4);

  prep_kernel<<<dim3(51024), dim3(256), 0, stream>>>(corpus, Cpk, patient, Wpe, bpe, q64, Qpk);
  sim_topk_mfma<<<dim3(8 * NCHUNK), dim3(256), 0, stream>>>(Qpk, Cpk, part_k);
  mr_tp_kernel<<<dim3(1280), dim3(256), 0, stream>>>(part_k, q64, corpus,
                                                     out_scores, out_idxf, topidx,
                                                     treatment, conf, Wte, bte, Wce, bce,
                                                     Wp1, bp1, Wp2, bp2, combined, out_prop);
  // r_enc = gather(corpus) @ Wre, K=4096 split 2x2048 -> p0,p1 (bre folded downstream)
  gemm64_kernel<0, true, false><<<dim3(8, 32), dim3(256), 0, stream>>>(
      (const float*)nullptr, (const float*)nullptr, (const float*)nullptr, (const float*)nullptr,
      topidx, corpus, Wre, 512, (const float*)nullptr, p0, p1, 512, 2048);
  // h1 = [combined | p0+p1+bre] @ Wo1, K=1536 split 2x768 -> pp0,pp1 (bo1+relu folded downstream)
  gemm64_kernel<1, true, false><<<dim3(8, 32), dim3(256), 0, stream>>>(
      combined, p0, p1, bre, (const int*)nullptr, (const float*)nullptr,
      Wo1, 512, (const float*)nullptr, pp0, pp1, 512, 768);
  // h2 = relu(relu(pp0+pp1+bo1) @ Wo2 + bo2), K=512
  gemm64_kernel<2, false, true><<<dim3(4, 16), dim3(256), 0, stream>>>(
      (const float*)nullptr, pp0, pp1, bo1, (const int*)nullptr, (const float*)nullptr,
      Wo2, 256, bo2, h2, (float*)nullptr, 256, 512);
  outcome_kernel<<<dim3(256), dim3(256), 0, stream>>>(h2, Wo3, bo3, out_outcome);
}

// Round 14
// 577.061 us; speedup vs baseline: 1.6660x; 1.1014x over previous
//
#include <hip/hip_runtime.h>
#include <math.h>

#define TOPK 8
#define NCORPUS 200000
#define BROWS 1024
#define CHUNK 512
#define NCHUNK 391           /* ceil(200000/512) */
#define NT 32                /* 4 subs * 8 K-steps (BK=64) */
#define NPART 4              /* per-chunk candidate depth */
#define NEGINF (-3.0e38f)

typedef __attribute__((ext_vector_type(8))) short bf16x8;
typedef __attribute__((ext_vector_type(4))) float f32x4;

__device__ __forceinline__ float wave_sum_f32(float v) {
#pragma unroll
  for (int m = 32; m >= 1; m >>= 1) v += __shfl_xor(v, m, 64);
  return v;
}
__device__ __forceinline__ double wave_sum_f64(double v) {
#pragma unroll
  for (int m = 32; m >= 1; m >>= 1) v += __shfl_xor(v, m, 64);
  return v;
}
__device__ __forceinline__ unsigned short f2bf(float f) {
  unsigned int u = __float_as_uint(f);
  unsigned int r = (u + 0x7fffu + ((u >> 16) & 1u)) >> 16;
  return (unsigned short)r;
}
__device__ __forceinline__ void gload16(const void* g, void* l) {
  __builtin_amdgcn_global_load_lds(
      (const __attribute__((address_space(1))) unsigned int*)g,
      (__attribute__((address_space(3))) unsigned int*)l, 16, 0, 0);
}
// 4-deep sorted-desc insert on tagged floats (max/min only)
__device__ __forceinline__ void kins4f(float (&S)[4], float v) {
#pragma unroll
  for (int p = 0; p < 4; ++p) {
    float mx = fmaxf(S[p], v);
    v = fminf(S[p], v);
    S[p] = mx;
  }
}
// merge two sorted-desc-4 float lists -> top-4 sorted desc (max/min network)
__device__ __forceinline__ void pmerge4f(float (&a)[4], const float (&b)[4]) {
  float c0 = fmaxf(a[0], b[3]), c1 = fmaxf(a[1], b[2]);
  float c2 = fmaxf(a[2], b[1]), c3 = fmaxf(a[3], b[0]);
  float t;
  t = fmaxf(c0, c2); c2 = fminf(c0, c2); c0 = t;
  t = fmaxf(c1, c3); c3 = fminf(c1, c3); c1 = t;
  t = fmaxf(c0, c1); c1 = fminf(c0, c1); c0 = t;
  t = fmaxf(c2, c3); c3 = fminf(c2, c3); c2 = t;
  a[0] = c0; a[1] = c1; a[2] = c2; a[3] = c3;
}

// ---------------- merged: corpus pack (0..49999) | q encode (50000..51023) | WreT pack (51024..51535) ----------------
__global__ void prep_kernel(const float* __restrict__ corpus, unsigned short* __restrict__ Cpk,
                            const float* __restrict__ patient, const float* __restrict__ Wpe,
                            const float* __restrict__ bpe, double* __restrict__ q64,
                            unsigned short* __restrict__ Qpk,
                            const float* __restrict__ Wre, unsigned short* __restrict__ WreT) {
  __shared__ float ps[66];
  __shared__ double red[4];
  __shared__ double s_den;
  __shared__ float tbuf[64 * 65];
  int tid = threadIdx.x;
  if (blockIdx.x < 50000) {
    int wid = tid >> 6, lane = tid & 63;
    int row = blockIdx.x * 4 + wid;
    if (row >= NCORPUS) return;
    const float4* p = (const float4*)(corpus + (size_t)row * 512);
    float4 a = p[lane * 2], b = p[lane * 2 + 1];
    float s = a.x * a.x + a.y * a.y + a.z * a.z + a.w * a.w +
              b.x * b.x + b.y * b.y + b.z * b.z + b.w * b.w;
    s = wave_sum_f32(s);
    float inv = 1.0f / fmaxf(sqrtf(s), 1e-12f);
    union { unsigned short us[8]; uint4 v; } pk;
    pk.us[0] = f2bf(a.x * inv); pk.us[1] = f2bf(a.y * inv);
    pk.us[2] = f2bf(a.z * inv); pk.us[3] = f2bf(a.w * inv);
    pk.us[4] = f2bf(b.x * inv); pk.us[5] = f2bf(b.y * inv);
    pk.us[6] = f2bf(b.z * inv); pk.us[7] = f2bf(b.w * inv);
    *(uint4*)(Cpk + (size_t)row * 512 + lane * 8) = pk.v;
  } else if (blockIdx.x < 51024) {
    int b = blockIdx.x - 50000;
    if (tid < 66) ps[tid] = patient[b * 66 + tid];
    __syncthreads();
    double v0 = (double)bpe[tid];
    double v1 = (double)bpe[tid + 256];
    for (int k = 0; k < 66; ++k) {
      double p = (double)ps[k];
      v0 += p * (double)Wpe[k * 512 + tid];
      v1 += p * (double)Wpe[k * 512 + tid + 256];
    }
    double ss = wave_sum_f64(v0 * v0 + v1 * v1);
    if ((tid & 63) == 0) red[tid >> 6] = ss;
    __syncthreads();
    if (tid == 0) s_den = fmax(sqrt(red[0] + red[1] + red[2] + red[3]), 1e-12);
    __syncthreads();
    double den = s_den;
    double o0 = v0 / den, o1 = v1 / den;
    q64[(size_t)b * 512 + tid] = o0;
    q64[(size_t)b * 512 + tid + 256] = o1;
    Qpk[(size_t)b * 512 + tid] = f2bf((float)o0);
    Qpk[(size_t)b * 512 + tid + 256] = f2bf((float)o1);
  } else {
    // WreT[n][k] = bf16(Wre[k][n]); 64x64 tiles
    int tb = blockIdx.x - 51024;
    int kt = tb >> 3, nt = tb & 7;
    int k0 = kt * 64, n0 = nt * 64;
    int r = tid >> 2, q = tid & 3;
#pragma unroll
    for (int i = 0; i < 4; ++i) {
      float4 v = *(const float4*)(Wre + (size_t)(k0 + r) * 512 + n0 + q * 16 + i * 4);
      float* d = tbuf + r * 65 + q * 16 + i * 4;
      d[0] = v.x; d[1] = v.y; d[2] = v.z; d[3] = v.w;
    }
    __syncthreads();
    int n = tid >> 2, s = tid & 3;
    union { unsigned short us[16]; uint4 v[2]; } ob;
#pragma unroll
    for (int j = 0; j < 16; ++j) ob.us[j] = f2bf(tbuf[(s * 16 + j) * 65 + n]);
    unsigned short* dst = WreT + (size_t)(n0 + n) * 4096 + k0 + s * 16;
    *(uint4*)dst = ob.v[0];
    *(uint4*)(dst + 8) = ob.v[1];
  }
}

// fold one sub's acc into tagged-float top-4 lists
template <bool CHECK>
__device__ __forceinline__ void fold_sub(f32x4 (&acc)[4][4], float (&lk)[4][4],
                                         int tagbase, int rb2) {
#pragma unroll
  for (int m = 0; m < 4; ++m)
#pragma unroll
    for (int j = 0; j < 4; ++j) {
      int mj = m * 16 + j;
      unsigned tg = (unsigned)(tagbase - mj);
      bool ok = true;
      if (CHECK) ok = (rb2 + mj) < NCORPUS;
#pragma unroll
      for (int n = 0; n < 4; ++n) {
        unsigned bb = (__float_as_uint(acc[m][n][j]) & 0xFFFFFC00u) | tg;
        float tf = __uint_as_float(bb);
        if (CHECK) tf = ok ? tf : NEGINF;
        kins4f(lk[n], tf);
      }
    }
}

// ---------------- sim^T GEMM via bf16 MFMA + tagged-float top-4 ----------------
__global__ __launch_bounds__(256, 2) void sim_topk_mfma(
    const unsigned short* __restrict__ Qpk, const unsigned short* __restrict__ Cpk,
    unsigned int* __restrict__ part_k) {
  __shared__ __align__(16) unsigned short smem[2][16384];  // [buf][As 8192 | Bs 8192] = 64 KiB

  int tid = threadIdx.x;
  int lane = tid & 63, wid = tid >> 6;
  int wr = wid >> 1, wc = wid & 1;
  int g = (blockIdx.x & 7) * NCHUNK + (blockIdx.x >> 3);
  int chunk = g >> 3, mt = g & 7;
  int m0 = mt * 128;
  int rbase = chunk * CHUNK;
  bool lastChunk = (rbase + CHUNK) > NCORPUS;

  int srow = tid >> 3;
  int scol = (((tid & 7) ^ (srow & 7)) << 3);

  int l15 = lane & 15, l4 = lane >> 4, l7 = lane & 7;
  int aoff[2][4], boff[2][4];
#pragma unroll
  for (int kk = 0; kk < 2; ++kk)
#pragma unroll
    for (int q = 0; q < 4; ++q) {
      int sw = (((kk * 4 + l4) ^ l7) << 3);
      aoff[kk][q] = (wr * 64 + q * 16 + l15) * 64 + sw;
      boff[kk][q] = 8192 + (wc * 64 + q * 16 + l15) * 64 + sw;
    }

  float lk[4][NPART];
#pragma unroll
  for (int n = 0; n < 4; ++n)
#pragma unroll
    for (int p = 0; p < NPART; ++p) lk[n][p] = NEGINF;

  f32x4 zero = {0.f, 0.f, 0.f, 0.f};
  f32x4 acc[4][4];
#pragma unroll
  for (int m = 0; m < 4; ++m)
#pragma unroll
    for (int n = 0; n < 4; ++n) acc[m][n] = zero;

  auto stageA = [&](int t, unsigned short* dst) {
    int sub = t >> 3, kt = t & 7;
    int rb = rbase + sub * 128;
    int k0 = kt * 64;
#pragma unroll
    for (int r = 0; r < 4; ++r) {
      int cr = rb + r * 32 + srow;
      if (cr > NCORPUS - 1) cr = NCORPUS - 1;
      gload16(Cpk + (size_t)cr * 512 + k0 + scol, dst + (r * 4 + wid) * 512);
    }
  };
  auto stageB = [&](int t, unsigned short* dst) {
    int kt = t & 7;
    int k0 = kt * 64;
#pragma unroll
    for (int r = 0; r < 4; ++r) {
      int qr = m0 + r * 32 + srow;
      gload16(Qpk + (size_t)qr * 512 + k0 + scol, dst + 8192 + (r * 4 + wid) * 512);
    }
  };

  stageA(0, smem[0]);
  stageB(0, smem[0]);

  for (int t = 0; t < NT; ++t) {
    int t1 = t + 1;
    if (t1 < NT) {
      unsigned short* nb = smem[t1 & 1];
      stageA(t1, nb);
      stageB(t1, nb);
      asm volatile("s_waitcnt vmcnt(8)" ::: "memory");
    } else {
      asm volatile("s_waitcnt vmcnt(0)" ::: "memory");
    }
    __builtin_amdgcn_s_barrier();
    const unsigned short* cb = smem[t & 1];
#pragma unroll
    for (int kk = 0; kk < 2; ++kk) {
      bf16x8 a[4], b[4];
#pragma unroll
      for (int m = 0; m < 4; ++m) a[m] = *(const bf16x8*)(cb + aoff[kk][m]);
#pragma unroll
      for (int n = 0; n < 4; ++n) b[n] = *(const bf16x8*)(cb + boff[kk][n]);
#pragma unroll
      for (int m = 0; m < 4; ++m)
#pragma unroll
        for (int n = 0; n < 4; ++n)
          acc[m][n] = __builtin_amdgcn_mfma_f32_16x16x32_bf16(a[m], b[n], acc[m][n], 0, 0, 0);
    }
    if ((t & 7) == 7) {
      int sub = t >> 3;
      int cellbase = sub * 128 + wr * 64 + l4 * 4;
      int rb2 = rbase + cellbase;
      int tagbase = (CHUNK - 1) - cellbase;
      if (lastChunk) fold_sub<true>(acc, lk, tagbase, rb2);
      else fold_sub<false>(acc, lk, tagbase, rb2);
#pragma unroll
      for (int m = 0; m < 4; ++m)
#pragma unroll
        for (int n = 0; n < 4; ++n) acc[m][n] = zero;
    }
    __builtin_amdgcn_s_barrier();
  }

#pragma unroll
  for (int rnd = 0; rnd < 2; ++rnd) {
    int msk = 16 << rnd;
#pragma unroll
    for (int n = 0; n < 4; ++n) {
      float ov[NPART];
#pragma unroll
      for (int p = 0; p < NPART; ++p) ov[p] = __shfl_xor(lk[n][p], msk, 64);
      pmerge4f(lk[n], ov);
    }
  }
  float* fb = (float*)&smem[0][0];
  if (wr == 1 && l4 == 0) {
#pragma unroll
    for (int n = 0; n < 4; ++n) {
      int col = wc * 64 + n * 16 + l15;
#pragma unroll
      for (int p = 0; p < NPART; ++p) fb[col * 4 + p] = lk[n][p];
    }
  }
  __syncthreads();
  if (wr == 0 && l4 == 0) {
#pragma unroll
    for (int n = 0; n < 4; ++n) {
      int col = wc * 64 + n * 16 + l15;
      float ov[NPART];
#pragma unroll
      for (int p = 0; p < NPART; ++p) ov[p] = fb[col * 4 + p];
      pmerge4f(lk[n], ov);
      size_t base = ((size_t)(m0 + col) * NCHUNK + chunk) * NPART;
#pragma unroll
      for (int p = 0; p < NPART; ++p) {
        unsigned bits = __float_as_uint(lk[n][p]);
        unsigned tag = bits & 0x3FFu;
        unsigned flip = bits ^ ((unsigned)((int)bits >> 31) | 0x80000000u);
        part_k[base + p] = (flip & 0xFFFFFC00u) | tag;
      }
    }
  }
}

// ---------------- merged: merge+refine (0..255, +rnorm) | tcenc+prop (256..1279) ----------------
__global__ __launch_bounds__(256, 2) void mr_tp_kernel(
    const unsigned int* __restrict__ part_k,
    const double* __restrict__ q64, const float* __restrict__ corpus,
    float* __restrict__ out_scores, float* __restrict__ out_idxf, int* __restrict__ topidx,
    float* __restrict__ rnorm,
    const float* __restrict__ treatment, const float* __restrict__ conf,
    const float* __restrict__ Wte, const float* __restrict__ bte,
    const float* __restrict__ Wce, const float* __restrict__ bce,
    const float* __restrict__ Wp1, const float* __restrict__ bp1,
    const float* __restrict__ Wp2, const float* __restrict__ bp2,
    float* __restrict__ combined, float* __restrict__ out_prop) {
  __shared__ float cs[64];
  __shared__ float red0[4], red1[4];
  int tid = threadIdx.x;
  if (blockIdx.x < 256) {
    int wv = tid >> 6, lane = tid & 63;
    int row = blockIdx.x * 4 + wv;
    if (row >= BROWS) return;

    unsigned tk[16]; int tm[16];
#pragma unroll
    for (int p = 0; p < 16; ++p) { tk[p] = 0u; tm[p] = 0; }
    const unsigned* base = part_k + (size_t)row * (NCHUNK * NPART);
    for (int e = lane; e < NCHUNK * NPART; e += 64) {
      unsigned k = base[e];
      if (k > tk[15]) {
        unsigned kv = k; int mv = e;
#pragma unroll
        for (int p = 0; p < 16; ++p) {
          bool gt = kv > tk[p];
          unsigned ts = tk[p]; int ti = tm[p];
          tk[p] = gt ? kv : ts; tm[p] = gt ? mv : ti;
          kv = gt ? ts : kv;    mv = gt ? ti : mv;
        }
      }
    }
#pragma unroll
    for (int r = 0; r < 6; ++r) {
      unsigned ov[16]; int om[16];
#pragma unroll
      for (int p = 0; p < 16; ++p) {
        ov[p] = __shfl_xor(tk[p], 1 << r, 64);
        om[p] = __shfl_xor(tm[p], 1 << r, 64);
      }
      unsigned cv[16]; int cm[16];
#pragma unroll
      for (int i = 0; i < 16; ++i) {
        bool t = tk[i] >= ov[15 - i];
        cv[i] = t ? tk[i] : ov[15 - i];
        cm[i] = t ? tm[i] : om[15 - i];
      }
#pragma unroll
      for (int s = 8; s >= 1; s >>= 1)
#pragma unroll
        for (int bb = 0; bb < 16; bb += 2 * s)
#pragma unroll
          for (int o = 0; o < s; ++o) {
            int x = bb + o, y = bb + o + s;
            bool t = cv[x] >= cv[y];
            unsigned hv = t ? cv[x] : cv[y]; unsigned lv = t ? cv[y] : cv[x];
            int hm = t ? cm[x] : cm[y];      int lm = t ? cm[y] : cm[x];
            cv[x] = hv; cm[x] = hm; cv[y] = lv; cm[y] = lm;
          }
#pragma unroll
      for (int i = 0; i < 16; ++i) { tk[i] = cv[i]; tm[i] = cm[i]; }
    }
    int cidx[16];
#pragma unroll
    for (int c = 0; c < 16; ++c) {
      int ic = ((tm[c] >> 2) << 9) + (CHUNK - 1) - (int)(tk[c] & 0x3FFu);
      if (ic > NCORPUS - 1) ic = NCORPUS - 1;
      if (ic < 0) ic = 0;
      cidx[c] = ic;
    }
    double qv[8];
    const double* qrow = q64 + (size_t)row * 512;
#pragma unroll
    for (int t = 0; t < 8; ++t) qv[t] = qrow[lane * 8 + t];
    double rs[16];
    float rn[16];
#pragma unroll
    for (int c = 0; c < 16; ++c) {
      const float* crow = corpus + (size_t)cidx[c] * 512 + lane * 8;
      double qd = 0.0, cd = 0.0;
#pragma unroll
      for (int t = 0; t < 8; ++t) {
        double x = (double)crow[t];
        cd += x * x;
        qd += qv[t] * x;
      }
      qd = wave_sum_f64(qd);
      cd = wave_sum_f64(cd);
      double nr = fmax(sqrt(cd), 1e-12);
      rs[c] = qd / nr;
      rn[c] = (float)nr;
    }
    if (lane == 0) {
      for (int o = 0; o < TOPK; ++o) {
        double bsc = -1e300;
        int bid2 = 0x7fffffff, bc = -1;
#pragma unroll
        for (int c = 0; c < 16; ++c) {
          bool better = (rs[c] > bsc) || (rs[c] == bsc && cidx[c] < bid2);
          if (better) { bsc = rs[c]; bid2 = cidx[c]; bc = c; }
        }
        out_scores[row * 8 + o] = (float)bsc;
        out_idxf[row * 8 + o] = (float)bid2;
        topidx[row * 8 + o] = bid2;
        rnorm[row * 8 + o] = rn[bc];
#pragma unroll
        for (int c = 0; c < 16; ++c)
          if (c == bc) rs[c] = -1e300;
      }
    }
  } else {
    int b = blockIdx.x - 256;
    if (tid < 64) cs[tid] = conf[b * 64 + tid];
    __syncthreads();
    float t0 = treatment[b * 2], t1 = treatment[b * 2 + 1];
    float l0 = 0.f, l1 = 0.f;
#pragma unroll
    for (int rep = 0; rep < 2; ++rep) {
      int h = tid + rep * 256;
      float te = fmaf(t0, Wte[h], fmaf(t1, Wte[512 + h], bte[h]));
      combined[(size_t)b * 1536 + h] = te;
      float ce = bce[h];
      float pv = bp1[h];
      for (int k = 0; k < 64; ++k) {
        float c = cs[k];
        ce = fmaf(c, Wce[k * 512 + h], ce);
        pv = fmaf(c, Wp1[k * 512 + h], pv);
      }
      combined[(size_t)b * 1536 + 512 + h] = ce;
      pv = fmaxf(pv, 0.f);
      l0 = fmaf(pv, Wp2[h * 2], l0);
      l1 = fmaf(pv, Wp2[h * 2 + 1], l1);
    }
    l0 = wave_sum_f32(l0);
    l1 = wave_sum_f32(l1);
    int wv = tid >> 6, lane = tid & 63;
    if (lane == 0) { red0[wv] = l0; red1[wv] = l1; }
    __syncthreads();
    if (tid == 0) {
      float a = red0[0] + red0[1] + red0[2] + red0[3] + bp2[0];
      float c2 = red1[0] + red1[1] + red1[2] + red1[3] + bp2[1];
      float m = fmaxf(a, c2);
      float e0 = expf(a - m), e1 = expf(c2 - m);
      float inv = 1.f / (e0 + e1);
      out_prop[b * 2] = e0 * inv;
      out_prop[b * 2 + 1] = e1 * inv;
    }
  }
}

// ---------------- r_enc via bf16 MFMA: gathered Cpk rows x WreT, per-segment rnorm rescale ----------------
// M=batch 128-tile, N=128-tile of Wre cols, K=4096 (8 segments of 512)
__global__ __launch_bounds__(256, 1) void renc_mfma(
    const unsigned short* __restrict__ Cpk, const unsigned short* __restrict__ WreT,
    const int* __restrict__ topidx, const float* __restrict__ rnorm,
    const float* __restrict__ bre, float* __restrict__ combined) {
  __shared__ __align__(16) unsigned short smem[2][16384];  // [buf][A 8192 | B 8192] ush = 64 KiB
  __shared__ int gi[1024];

  int tid = threadIdx.x;
  int lane = tid & 63, wid = tid >> 6;
  int wr = wid >> 1, wc = wid & 1;
  int m0 = (blockIdx.x >> 2) * 128;   // 8 m-tiles
  int n0 = (blockIdx.x & 3) * 128;    // 4 n-tiles

#pragma unroll
  for (int i = 0; i < 4; ++i) gi[tid + i * 256] = topidx[m0 * 8 + tid + i * 256];
  __syncthreads();

  int srow = tid >> 3;
  int scol = (((tid & 7) ^ (srow & 7)) << 3);
  int idxr[4][8];
#pragma unroll
  for (int r = 0; r < 4; ++r)
#pragma unroll
    for (int s = 0; s < 8; ++s) idxr[r][s] = gi[(r * 32 + srow) * 8 + s];

  int l15 = lane & 15, l4 = lane >> 4, l7 = lane & 7;
  int aoff[2][4], boff[2][4];
#pragma unroll
  for (int kk = 0; kk < 2; ++kk)
#pragma unroll
    for (int q = 0; q < 4; ++q) {
      int sw = (((kk * 4 + l4) ^ l7) << 3);
      aoff[kk][q] = (wr * 64 + q * 16 + l15) * 64 + sw;
      boff[kk][q] = 8192 + (wc * 64 + q * 16 + l15) * 64 + sw;
    }

  f32x4 zero = {0.f, 0.f, 0.f, 0.f};
  f32x4 acc[4][4], acc2[4][4];
#pragma unroll
  for (int m = 0; m < 4; ++m)
#pragma unroll
    for (int n = 0; n < 4; ++n) { acc[m][n] = zero; acc2[m][n] = zero; }

  auto stageA = [&](int t, unsigned short* dst) {
    int seg = t >> 3;
    int kk = (t & 7) * 64;
#pragma unroll
    for (int r = 0; r < 4; ++r)
      gload16(Cpk + (size_t)idxr[r][seg] * 512 + kk + scol, dst + (r * 4 + wid) * 512);
  };
  auto stageB = [&](int t, unsigned short* dst) {
    int k0 = t * 64;
#pragma unroll
    for (int r = 0; r < 4; ++r) {
      int nr = n0 + r * 32 + srow;
      gload16(WreT + (size_t)nr * 4096 + k0 + scol, dst + 8192 + (r * 4 + wid) * 512);
    }
  };

  stageA(0, smem[0]);
  stageB(0, smem[0]);

  for (int t = 0; t < 64; ++t) {
    int t1 = t + 1;
    if (t1 < 64) {
      unsigned short* nb = smem[t1 & 1];
      stageA(t1, nb);
      stageB(t1, nb);
      asm volatile("s_waitcnt vmcnt(8)" ::: "memory");
    } else {
      asm volatile("s_waitcnt vmcnt(0)" ::: "memory");
    }
    __builtin_amdgcn_s_barrier();
    const unsigned short* cb = smem[t & 1];
#pragma unroll
    for (int kk = 0; kk < 2; ++kk) {
      bf16x8 a[4], b[4];
#pragma unroll
      for (int m = 0; m < 4; ++m) a[m] = *(const bf16x8*)(cb + aoff[kk][m]);
#pragma unroll
      for (int n = 0; n < 4; ++n) b[n] = *(const bf16x8*)(cb + boff[kk][n]);
#pragma unroll
      for (int m = 0; m < 4; ++m)
#pragma unroll
        for (int n = 0; n < 4; ++n)
          acc[m][n] = __builtin_amdgcn_mfma_f32_16x16x32_bf16(a[m], b[n], acc[m][n], 0, 0, 0);
    }
    if ((t & 7) == 7) {  // segment boundary: rescale by rnorm and accumulate
      int seg = t >> 3;
#pragma unroll
      for (int m = 0; m < 4; ++m)
#pragma unroll
        for (int j = 0; j < 4; ++j) {
          int row = m0 + wr * 64 + m * 16 + l4 * 4 + j;
          float rn = rnorm[row * 8 + seg];
#pragma unroll
          for (int n = 0; n < 4; ++n) acc2[m][n][j] = fmaf(rn, acc[m][n][j], acc2[m][n][j]);
        }
#pragma unroll
      for (int m = 0; m < 4; ++m)
#pragma unroll
        for (int n = 0; n < 4; ++n) acc[m][n] = zero;
    }
    __builtin_amdgcn_s_barrier();
  }

#pragma unroll
  for (int m = 0; m < 4; ++m)
#pragma unroll
    for (int j = 0; j < 4; ++j) {
      int row = m0 + wr * 64 + m * 16 + l4 * 4 + j;
#pragma unroll
      for (int n = 0; n < 4; ++n) {
        int col = n0 + wc * 64 + n * 16 + l15;
        combined[(size_t)row * 1536 + 1024 + col] = acc2[m][n][j] + bre[col];
      }
    }
}

// ---------------- 64x64 fp32 GEMM, 4x4/thread, split-K dbuf ----------------
// RELUIN=false: A = plain matrix (lda)
// RELUIN=true:  A = relu(p0+p1+ab) (row length 512)
template <bool RELUIN>
__global__ __launch_bounds__(256, 2) void gemm64f(
    const float* __restrict__ A, int lda,
    const float* __restrict__ p0, const float* __restrict__ p1, const float* __restrict__ ab,
    const float* __restrict__ W, int ldw,
    float* __restrict__ C0, float* __restrict__ C1, int ldc, int Kspan) {
  __shared__ float As[2][32 * 68];
  __shared__ float Bs[2][32 * 72];
  int tid = threadIdx.x;
  int by = blockIdx.y;
  int m0 = (by >> 1) * 64;
  int kh = by & 1;
  int koff = kh * Kspan;
  float* Cout = kh ? C1 : C0;
  int n0 = blockIdx.x * 64;
  int nk = Kspan >> 5;

  int arow0 = tid >> 3, afc = tid & 7;
  int arow1 = arow0 + 32;
  int bkb0 = tid >> 4, bnf = tid & 15;
  int bkb1 = bkb0 + 16;

  auto stageA1 = [&](int row, int ks, int buf) {
    int kg = koff + ks * 32 + afc * 4;
    float4 v;
    if (RELUIN) {
      float4 x = *(const float4*)(p0 + (size_t)(m0 + row) * 512 + kg);
      float4 y = *(const float4*)(p1 + (size_t)(m0 + row) * 512 + kg);
      float4 z = *(const float4*)(ab + kg);
      v.x = fmaxf(x.x + y.x + z.x, 0.f); v.y = fmaxf(x.y + y.y + z.y, 0.f);
      v.z = fmaxf(x.z + y.z + z.z, 0.f); v.w = fmaxf(x.w + y.w + z.w, 0.f);
    } else {
      v = *(const float4*)(A + (size_t)(m0 + row) * lda + kg);
    }
    float* d = As[buf] + (afc * 4) * 68 + row;
    d[0] = v.x; d[68] = v.y; d[136] = v.z; d[204] = v.w;
  };
  auto stage = [&](int ks, int buf) {
    stageA1(arow0, ks, buf);
    stageA1(arow1, ks, buf);
    int kg0 = koff + ks * 32 + bkb0;
    *(float4*)(Bs[buf] + bkb0 * 72 + bnf * 4) =
        *(const float4*)(W + (size_t)kg0 * ldw + n0 + bnf * 4);
    int kg1 = koff + ks * 32 + bkb1;
    *(float4*)(Bs[buf] + bkb1 * 72 + bnf * 4) =
        *(const float4*)(W + (size_t)kg1 * ldw + n0 + bnf * 4);
  };

  float acc[4][4];
#pragma unroll
  for (int i = 0; i < 4; ++i)
#pragma unroll
    for (int j = 0; j < 4; ++j) acc[i][j] = 0.f;

  int tm = tid >> 4, tn = tid & 15;

  stage(0, 0);
  __syncthreads();
  for (int ks = 0; ks < nk; ++ks) {
    if (ks + 1 < nk) stage(ks + 1, (ks + 1) & 1);
    const float* as = As[ks & 1];
    const float* bs = Bs[ks & 1];
#pragma unroll
    for (int k = 0; k < 32; ++k) {
      float4 a4 = *(const float4*)(as + k * 68 + tm * 4);
      float4 b4 = *(const float4*)(bs + k * 72 + tn * 4);
      float av[4] = {a4.x, a4.y, a4.z, a4.w};
      float bv[4] = {b4.x, b4.y, b4.z, b4.w};
#pragma unroll
      for (int i = 0; i < 4; ++i)
#pragma unroll
        for (int j = 0; j < 4; ++j) acc[i][j] = fmaf(av[i], bv[j], acc[i][j]);
    }
    __syncthreads();
  }

#pragma unroll
  for (int i = 0; i < 4; ++i) {
    float4 v;
    v.x = acc[i][0]; v.y = acc[i][1]; v.z = acc[i][2]; v.w = acc[i][3];
    *(float4*)(Cout + (size_t)(m0 + tm * 4 + i) * ldc + n0 + tn * 4) = v;
  }
}

// ---------------- outcome head: h2 = relu(h2p0+h2p1+bo2); out = h2 @ Wo3 + bo3 ----------------
__global__ void outcome_kernel(const float* __restrict__ h2p0, const float* __restrict__ h2p1,
                               const float* __restrict__ bo2, const float* __restrict__ Wo3,
                               const float* __restrict__ bo3, float* __restrict__ out) {
  int wv = threadIdx.x >> 6, lane = threadIdx.x & 63;
  int row = blockIdx.x * 4 + wv;
  if (row >= BROWS) return;
  float4 a = ((const float4*)(h2p0 + (size_t)row * 256))[lane];
  float4 b = ((const float4*)(h2p1 + (size_t)row * 256))[lane];
  float4 c = ((const float4*)bo2)[lane];
  float4 w = ((const float4*)Wo3)[lane];
  float h0 = fmaxf(a.x + b.x + c.x, 0.f);
  float h1 = fmaxf(a.y + b.y + c.y, 0.f);
  float h2 = fmaxf(a.z + b.z + c.z, 0.f);
  float h3 = fmaxf(a.w + b.w + c.w, 0.f);
  float s = h0 * w.x + h1 * w.y + h2 * w.z + h3 * w.w;
  s = wave_sum_f32(s);
  if (lane == 0) out[row] = s + bo3[0];
}

extern "C" void kernel_launch(void* const* d_in, const int* in_sizes, int n_in,
                              void* d_out, int out_size, void* d_ws, size_t ws_size,
                              hipStream_t stream) {
  const float* treatment = (const float*)d_in[0];
  const float* conf = (const float*)d_in[1];
  const float* patient = (const float*)d_in[2];
  const float* corpus = (const float*)d_in[3];
  const float* Wpe = (const float*)d_in[4];
  const float* bpe = (const float*)d_in[5];
  const float* Wte = (const float*)d_in[6];
  const float* bte = (const float*)d_in[7];
  const float* Wce = (const float*)d_in[8];
  const float* bce = (const float*)d_in[9];
  const float* Wre = (const float*)d_in[10];
  const float* bre = (const float*)d_in[11];
  const float* Wo1 = (const float*)d_in[12];
  const float* bo1 = (const float*)d_in[13];
  const float* Wo2 = (const float*)d_in[14];
  const float* bo2 = (const float*)d_in[15];
  const float* Wo3 = (const float*)d_in[16];
  const float* bo3 = (const float*)d_in[17];
  const float* Wp1 = (const float*)d_in[18];
  const float* bp1 = (const float*)d_in[19];
  const float* Wp2 = (const float*)d_in[20];
  const float* bp2 = (const float*)d_in[21];

  float* out = (float*)d_out;
  float* out_outcome = out;                       // [1024]
  float* out_scores = out + 1024;                 // [1024*8]
  float* out_idxf = out + 1024 + 8192;            // [1024*8] (ints as float)
  float* out_prop = out + 1024 + 8192 + 8192;     // [1024*2]

  char* ws = (char*)d_ws;
  size_t off = 0;
  auto carve = [&](size_t bytes) {
    void* p = ws + off;
    off = (off + bytes + 255) & ~(size_t)255;
    return p;
  };
  double* q64 = (double*)carve((size_t)1024 * 512 * 8);
  unsigned short* Qpk = (unsigned short*)carve((size_t)1024 * 512 * 2);
  unsigned short* Cpk = (unsigned short*)carve((size_t)NCORPUS * 512 * 2);
  unsigned short* WreT = (unsigned short*)carve((size_t)512 * 4096 * 2);
  unsigned int* part_k = (unsigned int*)carve((size_t)1024 * NCHUNK * NPART * 4);
  int* topidx = (int*)carve((size_t)1024 * 8 * 4);
  float* rnorm = (float*)carve((size_t)1024 * 8 * 4);
  float* combined = (float*)carve((size_t)1024 * 1536 * 4);
  float* pp0 = (float*)carve((size_t)1024 * 512 * 4);
  float* pp1 = (float*)carve((size_t)1024 * 512 * 4);
  float* h2p0 = (float*)carve((size_t)1024 * 256 * 4);
  float* h2p1 = (float*)carve((size_t)1024 * 256 * 4);

  prep_kernel<<<dim3(51536), dim3(256), 0, stream>>>(corpus, Cpk, patient, Wpe, bpe, q64, Qpk,
                                                     Wre, WreT);
  sim_topk_mfma<<<dim3(8 * NCHUNK), dim3(256), 0, stream>>>(Qpk, Cpk, part_k);
  mr_tp_kernel<<<dim3(1280), dim3(256), 0, stream>>>(part_k, q64, corpus,
                                                     out_scores, out_idxf, topidx, rnorm,
                                                     treatment, conf, Wte, bte, Wce, bce,
                                                     Wp1, bp1, Wp2, bp2, combined, out_prop);
  renc_mfma<<<dim3(32), dim3(256), 0, stream>>>(Cpk, WreT, topidx, rnorm, bre, combined);
  // h1 partials: combined[1024x1536] @ Wo1, K split 2x768 -> pp0,pp1
  gemm64f<false><<<dim3(8, 32), dim3(256), 0, stream>>>(
      combined, 1536, (const float*)nullptr, (const float*)nullptr, (const float*)nullptr,
      Wo1, 512, pp0, pp1, 512, 768);
  // h2 partials: relu(pp0+pp1+bo1) @ Wo2, K split 2x256 -> h2p0,h2p1
  gemm64f<true><<<dim3(4, 32), dim3(256), 0, stream>>>(
      (const float*)nullptr, 0, pp0, pp1, bo1,
      Wo2, 256, h2p0, h2p1, 256, 256);
  outcome_kernel<<<dim3(256), dim3(256), 0, stream>>>(h2p0, h2p1, bo2, Wo3, bo3, out_outcome);
}